// Round 4
// baseline (1204.309 us; speedup 1.0000x reference)
//
#include <hip/hip_runtime.h>

// MDDNet GNN layer — round 4: persistent pipelined edge kernel + fast scan.
// N=20000, E=320000, D=128, H1=256, H2=512, H3=1024, K3=640.

constexpr int D  = 128;
constexpr int H1 = 256;
constexpr int H2 = 512;
constexpr int H3 = 1024;
constexpr int K3 = D + H2;   // 640

typedef short  bf16x8 __attribute__((ext_vector_type(8)));
typedef ushort u16x8  __attribute__((ext_vector_type(8)));
typedef float  f32x4  __attribute__((ext_vector_type(4)));

__device__ __forceinline__ float leaky(float x) { return x >= 0.f ? x : 0.01f * x; }

__device__ __forceinline__ ushort f2bf(float f) {
    unsigned u = __float_as_uint(f);
    u += 0x7FFFu + ((u >> 16) & 1u);
    return (ushort)(u >> 16);
}

__device__ __forceinline__ int swz(int row, int bytecol) {
    return bytecol ^ ((row & 7) << 4);
}

__device__ __forceinline__ f32x4 mfma16(bf16x8 a, bf16x8 b, f32x4 c) {
    return __builtin_amdgcn_mfma_f32_16x16x32_bf16(a, b, c, 0, 0, 0);
}

// ---------------------------------------------------------------------------
// Counting sort by dst. scatter also pre-gathers src/dst (kills the perm->src
// dependent-load chain in the edge kernel).
// ---------------------------------------------------------------------------
__global__ __launch_bounds__(256) void hist_kernel(
    const int* __restrict__ dst, int* __restrict__ cursor, int E)
{
    const int i = blockIdx.x * 256 + threadIdx.x;
    if (i < E) atomicAdd(&cursor[dst[i]], 1);
}

// single block, 1024 threads, 20 elems/thread serial + LDS Hillis-Steele
__global__ __launch_bounds__(1024) void scan_kernel(int* __restrict__ cursor, int n)
{
    __shared__ int sums[1024];
    const int tid  = threadIdx.x;
    const int base = tid * 20;
    int v[20];
    int s = 0;
    #pragma unroll
    for (int i = 0; i < 20; ++i) {
        const int idx = base + i;
        v[i] = (idx < n) ? cursor[idx] : 0;
        s += v[i];
    }
    sums[tid] = s;
    __syncthreads();
    int acc = s;
    for (int d = 1; d < 1024; d <<= 1) {
        const int t = (tid >= d) ? sums[tid - d] : 0;
        __syncthreads();
        acc += t;
        sums[tid] = acc;
        __syncthreads();
    }
    int run = acc - s;   // exclusive base for this thread
    #pragma unroll
    for (int i = 0; i < 20; ++i) {
        const int idx = base + i;
        if (idx < n) cursor[idx] = run;
        run += v[i];
    }
}

__global__ __launch_bounds__(256) void scatter_kernel(
    const int* __restrict__ src, const int* __restrict__ dst,
    int* __restrict__ cursor, int* __restrict__ se, int* __restrict__ de,
    int* __restrict__ pe, int E)
{
    const int i = blockIdx.x * 256 + threadIdx.x;
    if (i < E) {
        const int d   = dst[i];
        const int pos = atomicAdd(&cursor[d], 1);
        se[pos] = src[i];
        de[pos] = d;
        pe[pos] = i;
    }
}

// ---------------------------------------------------------------------------
// Pack fp32 W[K][Nc] into bf16 B-fragment tile order.
// ---------------------------------------------------------------------------
__global__ __launch_bounds__(256) void pack_weights(
    const float* __restrict__ W, ushort* __restrict__ Wp, int K, int Nc)
{
    const int KT    = K >> 5;
    const int total = (Nc >> 4) * KT * 64;
    const int idx   = blockIdx.x * 256 + threadIdx.x;
    if (idx >= total) return;
    const int l   = idx & 63;
    const int tt  = idx >> 6;
    const int ks  = tt % KT;
    const int ni  = tt / KT;
    const int col = ni * 16 + (l & 15);
    const int k0  = ks * 32 + (l >> 4) * 8;
    u16x8 u;
    #pragma unroll
    for (int j = 0; j < 8; ++j) u[j] = f2bf(W[(size_t)(k0 + j) * Nc + col]);
    *(u16x8*)(Wp + (size_t)idx * 8) = u;
}

// ---------------------------------------------------------------------------
// Persistent fused edge pipeline over dst-sorted edges.
// Per tile (64 edges): t = bf16(x0[se]*ea[pe]); m1 = leaky(t@W1+b1);
// m2 = leaky(m1@W2+b2); run-combined atomicAdd into aggr[de].
// Pipeline: indices(i+1) prefetched during GEMM1(i); x0/ea gathers(i+1)
// issued at iteration end (in flight across atomics + loop).
// ---------------------------------------------------------------------------
constexpr int TE = 64;

__global__ __launch_bounds__(256, 3) void edge_mlp_mfma(
    const float* __restrict__ x0, const float* __restrict__ ea,
    const int* __restrict__ se, const int* __restrict__ de,
    const int* __restrict__ pe,
    const ushort* __restrict__ W1p, const float* __restrict__ b1,
    const ushort* __restrict__ W2p, const float* __restrict__ b2,
    float* __restrict__ aggr, int ntiles)
{
    __shared__ __align__(16) ushort t_lds[TE * D];     // 16 KB
    __shared__ __align__(16) ushort m1_lds[TE * H1];   // 32 KB
    __shared__ int didx[2][TE];

    const int tid    = threadIdx.x;
    const int lane   = tid & 63;
    const int w      = tid >> 6;
    const int lr     = lane & 15;
    const int lg     = lane >> 4;
    const int stride = gridDim.x;
    const int srow   = tid >> 4;   // staging row base
    const int slot   = tid & 15;   // staging 16B-pair slot

    int tile = blockIdx.x;
    int buf  = 0;

    // ---- prologue: indices + gathers for first tile
    int sr[4], pr[4];
    {
        const int e0 = tile * TE;
        #pragma unroll
        for (int i = 0; i < 4; ++i) {
            const int row = i * 16 + srow;
            sr[i] = se[e0 + row];
            pr[i] = pe[e0 + row];
        }
        if (tid < TE) didx[0][tid] = de[e0 + tid];
    }
    float4 xv[4][2], ev[4][2];
    #pragma unroll
    for (int i = 0; i < 4; ++i) {
        const float4* xp = (const float4*)(x0 + (size_t)sr[i] * D + slot * 8);
        const float4* gp = (const float4*)(ea + (size_t)pr[i] * D + slot * 8);
        xv[i][0] = xp[0]; xv[i][1] = xp[1];
        ev[i][0] = gp[0]; ev[i][1] = gp[1];
    }

    while (true) {
        // ---- write t tile from staged regs
        #pragma unroll
        for (int i = 0; i < 4; ++i) {
            const int row = i * 16 + srow;
            u16x8 u;
            u[0] = f2bf(xv[i][0].x * ev[i][0].x);
            u[1] = f2bf(xv[i][0].y * ev[i][0].y);
            u[2] = f2bf(xv[i][0].z * ev[i][0].z);
            u[3] = f2bf(xv[i][0].w * ev[i][0].w);
            u[4] = f2bf(xv[i][1].x * ev[i][1].x);
            u[5] = f2bf(xv[i][1].y * ev[i][1].y);
            u[6] = f2bf(xv[i][1].z * ev[i][1].z);
            u[7] = f2bf(xv[i][1].w * ev[i][1].w);
            *(u16x8*)((char*)t_lds + row * 256 + swz(row, slot * 16)) = u;
        }
        __syncthreads();   // B1: t ready

        const int next = tile + stride;
        // ---- prefetch indices for next tile (hidden under GEMM1)
        if (next < ntiles) {
            const int ne0 = next * TE;
            #pragma unroll
            for (int i = 0; i < 4; ++i) {
                const int row = i * 16 + srow;
                sr[i] = se[ne0 + row];
                pr[i] = pe[ne0 + row];
            }
            if (tid < TE) didx[buf ^ 1][tid] = de[ne0 + tid];
        }

        // ---- GEMM1: m1 = leaky(t @ W1 + b1)
        {
            f32x4 acc[4][4];
            #pragma unroll
            for (int ntl = 0; ntl < 4; ++ntl) {
                const float b = b1[(w * 4 + ntl) * 16 + lr];
                #pragma unroll
                for (int mt = 0; mt < 4; ++mt) acc[mt][ntl] = (f32x4){b, b, b, b};
            }
            #pragma unroll
            for (int ks = 0; ks < 4; ++ks) {
                bf16x8 af[4];
                #pragma unroll
                for (int mt = 0; mt < 4; ++mt) {
                    const int row = mt * 16 + lr;
                    af[mt] = *(const bf16x8*)((const char*)t_lds + row * 256 +
                                              swz(row, ks * 64 + lg * 16));
                }
                #pragma unroll
                for (int ntl = 0; ntl < 4; ++ntl) {
                    const bf16x8 bf = *(const bf16x8*)(W1p +
                        ((size_t)((w * 4 + ntl) * 4 + ks) * 64 + lane) * 8);
                    #pragma unroll
                    for (int mt = 0; mt < 4; ++mt)
                        acc[mt][ntl] = mfma16(af[mt], bf, acc[mt][ntl]);
                }
            }
            #pragma unroll
            for (int mt = 0; mt < 4; ++mt)
                #pragma unroll
                for (int ntl = 0; ntl < 4; ++ntl)
                    #pragma unroll
                    for (int r = 0; r < 4; ++r) {
                        const int row = mt * 16 + lg * 4 + r;
                        const int col = (w * 4 + ntl) * 16 + lr;
                        *(ushort*)((char*)m1_lds + row * 512 + swz(row, col * 2)) =
                            f2bf(leaky(acc[mt][ntl][r]));
                    }
        }
        __syncthreads();   // B2: m1 ready, t free

        // ---- GEMM2 + run-combined atomic scatter
        int dnode[4][4];
        #pragma unroll
        for (int mt = 0; mt < 4; ++mt)
            #pragma unroll
            for (int r = 0; r < 4; ++r)
                dnode[mt][r] = didx[buf][mt * 16 + lg * 4 + r];

        #pragma unroll
        for (int g = 0; g < 2; ++g) {
            f32x4 acc[4][4];
            #pragma unroll
            for (int ntl = 0; ntl < 4; ++ntl) {
                const float b = b2[(w * 8 + g * 4 + ntl) * 16 + lr];
                #pragma unroll
                for (int mt = 0; mt < 4; ++mt) acc[mt][ntl] = (f32x4){b, b, b, b};
            }
            #pragma unroll
            for (int ks = 0; ks < 8; ++ks) {
                bf16x8 af[4];
                #pragma unroll
                for (int mt = 0; mt < 4; ++mt) {
                    const int row = mt * 16 + lr;
                    af[mt] = *(const bf16x8*)((const char*)m1_lds + row * 512 +
                                              swz(row, ks * 64 + lg * 16));
                }
                #pragma unroll
                for (int ntl = 0; ntl < 4; ++ntl) {
                    const bf16x8 bf = *(const bf16x8*)(W2p +
                        ((size_t)((w * 8 + g * 4 + ntl) * 8 + ks) * 64 + lane) * 8);
                    #pragma unroll
                    for (int mt = 0; mt < 4; ++mt)
                        acc[mt][ntl] = mfma16(af[mt], bf, acc[mt][ntl]);
                }
            }
            #pragma unroll
            for (int mt = 0; mt < 4; ++mt)
                #pragma unroll
                for (int ntl = 0; ntl < 4; ++ntl) {
                    const int col = (w * 8 + g * 4 + ntl) * 16 + lr;
                    float s = leaky(acc[mt][ntl][0]);
                    #pragma unroll
                    for (int r = 1; r < 4; ++r) {
                        const float v = leaky(acc[mt][ntl][r]);
                        if (dnode[mt][r] == dnode[mt][r - 1]) {
                            s += v;
                        } else {
                            atomicAdd(&aggr[(size_t)dnode[mt][r - 1] * H2 + col], s);
                            s = v;
                        }
                    }
                    atomicAdd(&aggr[(size_t)dnode[mt][3] * H2 + col], s);
                }
        }

        tile = next;
        buf ^= 1;
        if (tile >= ntiles) break;

        // ---- issue next tile's gathers (in flight across loop-around)
        #pragma unroll
        for (int i = 0; i < 4; ++i) {
            const float4* xp = (const float4*)(x0 + (size_t)sr[i] * D + slot * 8);
            const float4* gp = (const float4*)(ea + (size_t)pr[i] * D + slot * 8);
            xv[i][0] = xp[0]; xv[i][1] = xp[1];
            ev[i][0] = gp[0]; ev[i][1] = gp[1];
        }
    }
}

// ---------------------------------------------------------------------------
// h[N][1024] = bf16(leaky(concat(x0, aggr) @ W3 + b3))
// ---------------------------------------------------------------------------
constexpr int TN = 32;

__global__ __launch_bounds__(256) void node_mlp1_mfma(
    const float* __restrict__ x0, const float* __restrict__ aggr,
    const ushort* __restrict__ W3p, const float* __restrict__ b3,
    ushort* __restrict__ h)
{
    __shared__ __align__(16) ushort a_lds[TN * K3];  // 40 KB
    const int tid  = threadIdx.x;
    const int n0   = blockIdx.x * TN;
    const int ch   = blockIdx.y;
    const int lane = tid & 63;
    const int w    = tid >> 6;
    const int lr   = lane & 15;
    const int lg   = lane >> 4;

    #pragma unroll
    for (int i = 0; i < 10; ++i) {
        const int c    = i * 256 + tid;
        const int row  = c / 80;
        const int slot = c % 80;
        const float* sp = (slot < 16)
            ? x0   + (size_t)(n0 + row) * D  + slot * 8
            : aggr + (size_t)(n0 + row) * H2 + (slot - 16) * 8;
        const float4 va = ((const float4*)sp)[0];
        const float4 vb = ((const float4*)sp)[1];
        u16x8 u;
        u[0] = f2bf(va.x); u[1] = f2bf(va.y); u[2] = f2bf(va.z); u[3] = f2bf(va.w);
        u[4] = f2bf(vb.x); u[5] = f2bf(vb.y); u[6] = f2bf(vb.z); u[7] = f2bf(vb.w);
        *(u16x8*)((char*)a_lds + row * 1280 + swz(row, slot * 16)) = u;
    }
    __syncthreads();

    #pragma unroll
    for (int g = 0; g < 2; ++g) {
        f32x4 acc[2][4];
        #pragma unroll
        for (int ntl = 0; ntl < 4; ++ntl) {
            const int colg = ch * 512 + (w * 8 + g * 4 + ntl) * 16 + lr;
            const float b = b3[colg];
            #pragma unroll
            for (int mt = 0; mt < 2; ++mt) acc[mt][ntl] = (f32x4){b, b, b, b};
        }
        for (int ks = 0; ks < 20; ++ks) {
            bf16x8 af[2];
            #pragma unroll
            for (int mt = 0; mt < 2; ++mt) {
                const int row = mt * 16 + lr;
                af[mt] = *(const bf16x8*)((const char*)a_lds + row * 1280 +
                                          swz(row, ks * 64 + lg * 16));
            }
            #pragma unroll
            for (int ntl = 0; ntl < 4; ++ntl) {
                const int nt = ch * 32 + w * 8 + g * 4 + ntl;
                const bf16x8 bf = *(const bf16x8*)(W3p +
                    ((size_t)(nt * 20 + ks) * 64 + lane) * 8);
                #pragma unroll
                for (int mt = 0; mt < 2; ++mt)
                    acc[mt][ntl] = mfma16(af[mt], bf, acc[mt][ntl]);
            }
        }
        #pragma unroll
        for (int mt = 0; mt < 2; ++mt)
            #pragma unroll
            for (int ntl = 0; ntl < 4; ++ntl) {
                const int colg = ch * 512 + (w * 8 + g * 4 + ntl) * 16 + lr;
                #pragma unroll
                for (int r = 0; r < 4; ++r) {
                    const int row = n0 + mt * 16 + lg * 4 + r;
                    h[(size_t)row * H3 + colg] = f2bf(leaky(acc[mt][ntl][r]));
                }
            }
    }
}

// ---------------------------------------------------------------------------
// out = ((h @ W4 + b4)·BN + x0) / 2
// ---------------------------------------------------------------------------
__global__ __launch_bounds__(256) void node_mlp2_mfma(
    const ushort* __restrict__ h, const float* __restrict__ x0,
    const ushort* __restrict__ W4p, const float* __restrict__ b4,
    const float* __restrict__ gamma, const float* __restrict__ beta,
    const float* __restrict__ mean, const float* __restrict__ var,
    float* __restrict__ out)
{
    const int tid  = threadIdx.x;
    const int n0   = blockIdx.x * TN;
    const int lane = tid & 63;
    const int w    = tid >> 6;
    const int lr   = lane & 15;
    const int lg   = lane >> 4;

    f32x4 acc[2][2];
    #pragma unroll
    for (int ntl = 0; ntl < 2; ++ntl) {
        const float b = b4[(w * 2 + ntl) * 16 + lr];
        #pragma unroll
        for (int mt = 0; mt < 2; ++mt) acc[mt][ntl] = (f32x4){b, b, b, b};
    }
    for (int ks = 0; ks < 32; ++ks) {
        bf16x8 af[2];
        #pragma unroll
        for (int mt = 0; mt < 2; ++mt)
            af[mt] = *(const bf16x8*)(h + (size_t)(n0 + mt * 16 + lr) * H3 +
                                      ks * 32 + lg * 8);
        #pragma unroll
        for (int ntl = 0; ntl < 2; ++ntl) {
            const bf16x8 bf = *(const bf16x8*)(W4p +
                ((size_t)((w * 2 + ntl) * 32 + ks) * 64 + lane) * 8);
            #pragma unroll
            for (int mt = 0; mt < 2; ++mt)
                acc[mt][ntl] = mfma16(af[mt], bf, acc[mt][ntl]);
        }
    }
    #pragma unroll
    for (int ntl = 0; ntl < 2; ++ntl) {
        const int col = (w * 2 + ntl) * 16 + lr;
        const float sc = gamma[col] * rsqrtf(var[col] + 1e-5f);
        const float bo = beta[col] - mean[col] * sc;
        #pragma unroll
        for (int mt = 0; mt < 2; ++mt)
            #pragma unroll
            for (int r = 0; r < 4; ++r) {
                const int row = n0 + mt * 16 + lg * 4 + r;
                const float v = acc[mt][ntl][r] * sc + bo;
                out[(size_t)row * D + col] =
                    0.5f * (v + x0[(size_t)row * D + col]);
            }
    }
}

extern "C" void kernel_launch(void* const* d_in, const int* in_sizes, int n_in,
                              void* d_out, int out_size, void* d_ws, size_t ws_size,
                              hipStream_t stream)
{
    const float* x0    = (const float*)d_in[0];
    const int*   ei    = (const int*)d_in[1];
    const float* ea    = (const float*)d_in[2];
    const float* W1    = (const float*)d_in[3];
    const float* b1    = (const float*)d_in[4];
    const float* W2    = (const float*)d_in[5];
    const float* b2    = (const float*)d_in[6];
    const float* W3    = (const float*)d_in[7];
    const float* b3    = (const float*)d_in[8];
    const float* W4    = (const float*)d_in[9];
    const float* b4    = (const float*)d_in[10];
    const float* gamma = (const float*)d_in[11];
    const float* beta  = (const float*)d_in[12];
    const float* mean  = (const float*)d_in[13];
    const float* var   = (const float*)d_in[14];
    float* out = (float*)d_out;

    const int N = in_sizes[0] / D;   // 20000
    const int E = in_sizes[2] / D;   // 320000
    const int* src = ei;
    const int* dst = ei + E;

    char* ws = (char*)d_ws;
    float*  aggr = (float*)ws;                                   // N*H2 f32
    ushort* h    = (ushort*)(ws + (size_t)N * H2 * 4);           // N*H3 bf16
    // sort scratch aliases h (h written only by node_mlp1, after edge kernel)
    int* cursor = (int*)h;             // N
    int* se     = cursor + N;          // E (sorted src)
    int* de     = se + E;              // E (sorted dst)
    int* pe     = de + E;              // E (sorted original edge id)
    ushort* W1p  = (ushort*)(ws + (size_t)N * H2 * 4 + (size_t)N * H3 * 2);
    ushort* W2p  = W1p + (size_t)(D  / 32) * (H1 / 16) * 512;
    ushort* W3p  = W2p + (size_t)(H1 / 32) * (H2 / 16) * 512;
    ushort* W4p  = W3p + (size_t)(K3 / 32) * (H3 / 16) * 512;

    hipMemsetAsync(aggr, 0, (size_t)N * H2 * sizeof(float), stream);
    hipMemsetAsync(cursor, 0, (size_t)N * sizeof(int), stream);

    pack_weights<<<(4096  + 255) / 256, 256, 0, stream>>>(W1, W1p, D,  H1);
    pack_weights<<<(16384 + 255) / 256, 256, 0, stream>>>(W2, W2p, H1, H2);
    pack_weights<<<(81920 + 255) / 256, 256, 0, stream>>>(W3, W3p, K3, H3);
    pack_weights<<<(16384 + 255) / 256, 256, 0, stream>>>(W4, W4p, H3, D);

    hist_kernel<<<(E + 255) / 256, 256, 0, stream>>>(dst, cursor, E);
    scan_kernel<<<1, 1024, 0, stream>>>(cursor, N);
    scatter_kernel<<<(E + 255) / 256, 256, 0, stream>>>(src, dst, cursor,
                                                        se, de, pe, E);

    const int ntiles = E / TE;                  // 5000
    const int grid_e = (ntiles < 768) ? ntiles : 768;
    edge_mlp_mfma<<<grid_e, 256, 0, stream>>>(x0, ea, se, de, pe,
                                              W1p, b1, W2p, b2, aggr, ntiles);
    dim3 g1(N / TN, 2);
    node_mlp1_mfma<<<g1, 256, 0, stream>>>(x0, aggr, W3p, b3, h);
    node_mlp2_mfma<<<N / TN, 256, 0, stream>>>(h, x0, W4p, b4, gamma, beta, mean, var, out);
}

// Round 5
// 720.223 us; speedup vs baseline: 1.6721x; 1.6721x over previous
//
#include <hip/hip_runtime.h>

// MDDNet GNN layer — round 5: decoupled gather (streaming) + dense edge GEMM
// with global_load_lds staging. Node kernels unchanged from round 3.
// N=20000, E=320000, D=128, H1=256, H2=512, H3=1024, K3=640.
//
// R4 lesson: __launch_bounds__(256,3) + 64 VGPRs of gather staging => scratch
// spills (FETCH 1.44GB). No register staging across long live ranges; no
// min-wave hints here.

constexpr int D  = 128;
constexpr int H1 = 256;
constexpr int H2 = 512;
constexpr int H3 = 1024;
constexpr int K3 = D + H2;   // 640

typedef short  bf16x8 __attribute__((ext_vector_type(8)));
typedef ushort u16x8  __attribute__((ext_vector_type(8)));
typedef float  f32x4  __attribute__((ext_vector_type(4)));

__device__ __forceinline__ float leaky(float x) { return x >= 0.f ? x : 0.01f * x; }

__device__ __forceinline__ ushort f2bf(float f) {
    unsigned u = __float_as_uint(f);
    u += 0x7FFFu + ((u >> 16) & 1u);
    return (ushort)(u >> 16);
}

// LDS XOR swizzle (T2/G4): XOR bits 4..6 of the byte offset with row&7
__device__ __forceinline__ int swz(int row, int bytecol) {
    return bytecol ^ ((row & 7) << 4);
}

__device__ __forceinline__ f32x4 mfma16(bf16x8 a, bf16x8 b, f32x4 c) {
    return __builtin_amdgcn_mfma_f32_16x16x32_bf16(a, b, c, 0, 0, 0);
}

// async global->LDS, 16B per lane (per-lane global src, wave-uniform LDS base)
__device__ __forceinline__ void gload_lds16(const void* g, void* l) {
    __builtin_amdgcn_global_load_lds(
        (const __attribute__((address_space(1))) void*)g,
        (__attribute__((address_space(3))) void*)l, 16, 0, 0);
}

// ---------------------------------------------------------------------------
// Counting sort by dst (hist -> block scan -> scatter with pre-gather).
// ---------------------------------------------------------------------------
__global__ __launch_bounds__(256) void hist_kernel(
    const int* __restrict__ dst, int* __restrict__ cursor, int E)
{
    const int i = blockIdx.x * 256 + threadIdx.x;
    if (i < E) atomicAdd(&cursor[dst[i]], 1);
}

__global__ __launch_bounds__(1024) void scan_kernel(int* __restrict__ cursor, int n)
{
    __shared__ int sums[1024];
    const int tid  = threadIdx.x;
    const int base = tid * 20;
    int v[20];
    int s = 0;
    #pragma unroll
    for (int i = 0; i < 20; ++i) {
        const int idx = base + i;
        v[i] = (idx < n) ? cursor[idx] : 0;
        s += v[i];
    }
    sums[tid] = s;
    __syncthreads();
    int acc = s;
    for (int d = 1; d < 1024; d <<= 1) {
        const int t = (tid >= d) ? sums[tid - d] : 0;
        __syncthreads();
        acc += t;
        sums[tid] = acc;
        __syncthreads();
    }
    int run = acc - s;
    #pragma unroll
    for (int i = 0; i < 20; ++i) {
        const int idx = base + i;
        if (idx < n) cursor[idx] = run;
        run += v[i];
    }
}

__global__ __launch_bounds__(256) void scatter_kernel(
    const int* __restrict__ src, const int* __restrict__ dst,
    int* __restrict__ cursor, int* __restrict__ se, int* __restrict__ de,
    int* __restrict__ pe, int E)
{
    const int i = blockIdx.x * 256 + threadIdx.x;
    if (i < E) {
        const int d   = dst[i];
        const int pos = atomicAdd(&cursor[d], 1);
        se[pos] = src[i];
        de[pos] = d;
        pe[pos] = i;
    }
}

// ---------------------------------------------------------------------------
// gather_t: t[pos] = bf16(x0[se[pos]] * ea[pe[pos]]), PRE-SWIZZLED chunks.
// One thread per 16B chunk; pure streaming, latency hidden by TLP.
// ---------------------------------------------------------------------------
__global__ __launch_bounds__(256) void gather_t(
    const float* __restrict__ x0, const float* __restrict__ ea,
    const int* __restrict__ se, const int* __restrict__ pe,
    ushort* __restrict__ t)
{
    const int gid  = blockIdx.x * 256 + threadIdx.x;
    const int e    = gid >> 4;
    const int slot = gid & 15;
    const int s = se[e];
    const int p = pe[e];
    const float4* xp = (const float4*)(x0 + (size_t)s * D + slot * 8);
    const float4* gp = (const float4*)(ea + (size_t)p * D + slot * 8);
    const float4 xa = xp[0], xb = xp[1];
    const float4 ga = gp[0], gb = gp[1];
    u16x8 u;
    u[0] = f2bf(xa.x * ga.x); u[1] = f2bf(xa.y * ga.y);
    u[2] = f2bf(xa.z * ga.z); u[3] = f2bf(xa.w * ga.w);
    u[4] = f2bf(xb.x * gb.x); u[5] = f2bf(xb.y * gb.y);
    u[6] = f2bf(xb.z * gb.z); u[7] = f2bf(xb.w * gb.w);
    const int slot_w = slot ^ (e & 7);   // pre-apply the LDS swizzle
    *(u16x8*)(t + (size_t)e * D + slot_w * 8) = u;
}

// ---------------------------------------------------------------------------
// Pack fp32 W[K][Nc] into bf16 B-fragment tile order.
// ---------------------------------------------------------------------------
__global__ __launch_bounds__(256) void pack_weights(
    const float* __restrict__ W, ushort* __restrict__ Wp, int K, int Nc)
{
    const int KT    = K >> 5;
    const int total = (Nc >> 4) * KT * 64;
    const int idx   = blockIdx.x * 256 + threadIdx.x;
    if (idx >= total) return;
    const int l   = idx & 63;
    const int tt  = idx >> 6;
    const int ks  = tt % KT;
    const int ni  = tt / KT;
    const int col = ni * 16 + (l & 15);
    const int k0  = ks * 32 + (l >> 4) * 8;
    u16x8 u;
    #pragma unroll
    for (int j = 0; j < 8; ++j) u[j] = f2bf(W[(size_t)(k0 + j) * Nc + col]);
    *(u16x8*)(Wp + (size_t)idx * 8) = u;
}

// ---------------------------------------------------------------------------
// Dense edge GEMM: stage t tile (16KB, async, swizzle pre-baked) ->
// m1 = leaky(t@W1+b1) -> m2 = leaky(m1@W2+b2) -> run-combined atomics.
// ---------------------------------------------------------------------------
constexpr int TE = 64;

__global__ __launch_bounds__(256) void edge_gemm_mfma(
    const ushort* __restrict__ t, const int* __restrict__ de,
    const ushort* __restrict__ W1p, const float* __restrict__ b1,
    const ushort* __restrict__ W2p, const float* __restrict__ b2,
    float* __restrict__ aggr)
{
    __shared__ __align__(16) ushort t_lds[TE * D];     // 16 KB
    __shared__ __align__(16) ushort m1_lds[TE * H1];   // 32 KB
    __shared__ int didx[TE];

    const int tid  = threadIdx.x;
    const int e0   = blockIdx.x * TE;
    const int lane = tid & 63;
    const int w    = tid >> 6;
    const int lr   = lane & 15;
    const int lg   = lane >> 4;

    // async stage: 4 waves x 4 calls x (64 lanes x 16B) = 16 KB
    const ushort* gsrc = t + (size_t)e0 * D;
    #pragma unroll
    for (int i = 0; i < 4; ++i) {
        const int c = (w * 4 + i) * 64 + lane;       // 16B chunk index
        gload_lds16(gsrc + (size_t)c * 8, t_lds + (w * 4 + i) * 512);
    }
    if (tid < TE) didx[tid] = de[e0 + tid];
    __syncthreads();   // drains vmcnt -> t_lds ready

    // GEMM1: m1[64][256] = leaky(t @ W1 + b1)
    {
        f32x4 acc[4][4];
        #pragma unroll
        for (int ntl = 0; ntl < 4; ++ntl) {
            const float b = b1[(w * 4 + ntl) * 16 + lr];
            #pragma unroll
            for (int mt = 0; mt < 4; ++mt) acc[mt][ntl] = (f32x4){b, b, b, b};
        }
        #pragma unroll
        for (int ks = 0; ks < 4; ++ks) {
            bf16x8 af[4];
            #pragma unroll
            for (int mt = 0; mt < 4; ++mt) {
                const int row = mt * 16 + lr;
                af[mt] = *(const bf16x8*)((const char*)t_lds + row * 256 +
                                          swz(row, ks * 64 + lg * 16));
            }
            #pragma unroll
            for (int ntl = 0; ntl < 4; ++ntl) {
                const bf16x8 bf = *(const bf16x8*)(W1p +
                    ((size_t)((w * 4 + ntl) * 4 + ks) * 64 + lane) * 8);
                #pragma unroll
                for (int mt = 0; mt < 4; ++mt)
                    acc[mt][ntl] = mfma16(af[mt], bf, acc[mt][ntl]);
            }
        }
        #pragma unroll
        for (int mt = 0; mt < 4; ++mt)
            #pragma unroll
            for (int ntl = 0; ntl < 4; ++ntl)
                #pragma unroll
                for (int r = 0; r < 4; ++r) {
                    const int row = mt * 16 + lg * 4 + r;
                    const int col = (w * 4 + ntl) * 16 + lr;
                    *(ushort*)((char*)m1_lds + row * 512 + swz(row, col * 2)) =
                        f2bf(leaky(acc[mt][ntl][r]));
                }
    }
    __syncthreads();

    // GEMM2 + run-combined atomic scatter (dst-sorted => runs combine)
    int dnode[4][4];
    #pragma unroll
    for (int mt = 0; mt < 4; ++mt)
        #pragma unroll
        for (int r = 0; r < 4; ++r)
            dnode[mt][r] = didx[mt * 16 + lg * 4 + r];

    #pragma unroll
    for (int g = 0; g < 2; ++g) {
        f32x4 acc[4][4];
        #pragma unroll
        for (int ntl = 0; ntl < 4; ++ntl) {
            const float b = b2[(w * 8 + g * 4 + ntl) * 16 + lr];
            #pragma unroll
            for (int mt = 0; mt < 4; ++mt) acc[mt][ntl] = (f32x4){b, b, b, b};
        }
        #pragma unroll
        for (int ks = 0; ks < 8; ++ks) {
            bf16x8 af[4];
            #pragma unroll
            for (int mt = 0; mt < 4; ++mt) {
                const int row = mt * 16 + lr;
                af[mt] = *(const bf16x8*)((const char*)m1_lds + row * 512 +
                                          swz(row, ks * 64 + lg * 16));
            }
            #pragma unroll
            for (int ntl = 0; ntl < 4; ++ntl) {
                const bf16x8 bf = *(const bf16x8*)(W2p +
                    ((size_t)((w * 8 + g * 4 + ntl) * 8 + ks) * 64 + lane) * 8);
                #pragma unroll
                for (int mt = 0; mt < 4; ++mt)
                    acc[mt][ntl] = mfma16(af[mt], bf, acc[mt][ntl]);
            }
        }
        #pragma unroll
        for (int mt = 0; mt < 4; ++mt)
            #pragma unroll
            for (int ntl = 0; ntl < 4; ++ntl) {
                const int col = (w * 8 + g * 4 + ntl) * 16 + lr;
                float s = leaky(acc[mt][ntl][0]);
                #pragma unroll
                for (int r = 1; r < 4; ++r) {
                    const float v = leaky(acc[mt][ntl][r]);
                    if (dnode[mt][r] == dnode[mt][r - 1]) {
                        s += v;
                    } else {
                        atomicAdd(&aggr[(size_t)dnode[mt][r - 1] * H2 + col], s);
                        s = v;
                    }
                }
                atomicAdd(&aggr[(size_t)dnode[mt][3] * H2 + col], s);
            }
    }
}

// ---------------------------------------------------------------------------
// h[N][1024] = bf16(leaky(concat(x0, aggr) @ W3 + b3))
// ---------------------------------------------------------------------------
constexpr int TN = 32;

__global__ __launch_bounds__(256) void node_mlp1_mfma(
    const float* __restrict__ x0, const float* __restrict__ aggr,
    const ushort* __restrict__ W3p, const float* __restrict__ b3,
    ushort* __restrict__ h)
{
    __shared__ __align__(16) ushort a_lds[TN * K3];  // 40 KB
    const int tid  = threadIdx.x;
    const int n0   = blockIdx.x * TN;
    const int ch   = blockIdx.y;
    const int lane = tid & 63;
    const int w    = tid >> 6;
    const int lr   = lane & 15;
    const int lg   = lane >> 4;

    #pragma unroll
    for (int i = 0; i < 10; ++i) {
        const int c    = i * 256 + tid;
        const int row  = c / 80;
        const int slot = c % 80;
        const float* sp = (slot < 16)
            ? x0   + (size_t)(n0 + row) * D  + slot * 8
            : aggr + (size_t)(n0 + row) * H2 + (slot - 16) * 8;
        const float4 va = ((const float4*)sp)[0];
        const float4 vb = ((const float4*)sp)[1];
        u16x8 u;
        u[0] = f2bf(va.x); u[1] = f2bf(va.y); u[2] = f2bf(va.z); u[3] = f2bf(va.w);
        u[4] = f2bf(vb.x); u[5] = f2bf(vb.y); u[6] = f2bf(vb.z); u[7] = f2bf(vb.w);
        *(u16x8*)((char*)a_lds + row * 1280 + swz(row, slot * 16)) = u;
    }
    __syncthreads();

    #pragma unroll
    for (int g = 0; g < 2; ++g) {
        f32x4 acc[2][4];
        #pragma unroll
        for (int ntl = 0; ntl < 4; ++ntl) {
            const int colg = ch * 512 + (w * 8 + g * 4 + ntl) * 16 + lr;
            const float b = b3[colg];
            #pragma unroll
            for (int mt = 0; mt < 2; ++mt) acc[mt][ntl] = (f32x4){b, b, b, b};
        }
        for (int ks = 0; ks < 20; ++ks) {
            bf16x8 af[2];
            #pragma unroll
            for (int mt = 0; mt < 2; ++mt) {
                const int row = mt * 16 + lr;
                af[mt] = *(const bf16x8*)((const char*)a_lds + row * 1280 +
                                          swz(row, ks * 64 + lg * 16));
            }
            #pragma unroll
            for (int ntl = 0; ntl < 4; ++ntl) {
                const int nt = ch * 32 + w * 8 + g * 4 + ntl;
                const bf16x8 bf = *(const bf16x8*)(W3p +
                    ((size_t)(nt * 20 + ks) * 64 + lane) * 8);
                #pragma unroll
                for (int mt = 0; mt < 2; ++mt)
                    acc[mt][ntl] = mfma16(af[mt], bf, acc[mt][ntl]);
            }
        }
        #pragma unroll
        for (int mt = 0; mt < 2; ++mt)
            #pragma unroll
            for (int ntl = 0; ntl < 4; ++ntl) {
                const int colg = ch * 512 + (w * 8 + g * 4 + ntl) * 16 + lr;
                #pragma unroll
                for (int r = 0; r < 4; ++r) {
                    const int row = n0 + mt * 16 + lg * 4 + r;
                    h[(size_t)row * H3 + colg] = f2bf(leaky(acc[mt][ntl][r]));
                }
            }
    }
}

// ---------------------------------------------------------------------------
// out = ((h @ W4 + b4)·BN + x0) / 2
// ---------------------------------------------------------------------------
__global__ __launch_bounds__(256) void node_mlp2_mfma(
    const ushort* __restrict__ h, const float* __restrict__ x0,
    const ushort* __restrict__ W4p, const float* __restrict__ b4,
    const float* __restrict__ gamma, const float* __restrict__ beta,
    const float* __restrict__ mean, const float* __restrict__ var,
    float* __restrict__ out)
{
    const int tid  = threadIdx.x;
    const int n0   = blockIdx.x * TN;
    const int lane = tid & 63;
    const int w    = tid >> 6;
    const int lr   = lane & 15;
    const int lg   = lane >> 4;

    f32x4 acc[2][2];
    #pragma unroll
    for (int ntl = 0; ntl < 2; ++ntl) {
        const float b = b4[(w * 2 + ntl) * 16 + lr];
        #pragma unroll
        for (int mt = 0; mt < 2; ++mt) acc[mt][ntl] = (f32x4){b, b, b, b};
    }
    for (int ks = 0; ks < 32; ++ks) {
        bf16x8 af[2];
        #pragma unroll
        for (int mt = 0; mt < 2; ++mt)
            af[mt] = *(const bf16x8*)(h + (size_t)(n0 + mt * 16 + lr) * H3 +
                                      ks * 32 + lg * 8);
        #pragma unroll
        for (int ntl = 0; ntl < 2; ++ntl) {
            const bf16x8 bf = *(const bf16x8*)(W4p +
                ((size_t)((w * 2 + ntl) * 32 + ks) * 64 + lane) * 8);
            #pragma unroll
            for (int mt = 0; mt < 2; ++mt)
                acc[mt][ntl] = mfma16(af[mt], bf, acc[mt][ntl]);
        }
    }
    #pragma unroll
    for (int ntl = 0; ntl < 2; ++ntl) {
        const int col = (w * 2 + ntl) * 16 + lr;
        const float sc = gamma[col] * rsqrtf(var[col] + 1e-5f);
        const float bo = beta[col] - mean[col] * sc;
        #pragma unroll
        for (int mt = 0; mt < 2; ++mt)
            #pragma unroll
            for (int r = 0; r < 4; ++r) {
                const int row = n0 + mt * 16 + lg * 4 + r;
                const float v = acc[mt][ntl][r] * sc + bo;
                out[(size_t)row * D + col] =
                    0.5f * (v + x0[(size_t)row * D + col]);
            }
    }
}

extern "C" void kernel_launch(void* const* d_in, const int* in_sizes, int n_in,
                              void* d_out, int out_size, void* d_ws, size_t ws_size,
                              hipStream_t stream)
{
    const float* x0    = (const float*)d_in[0];
    const int*   ei    = (const int*)d_in[1];
    const float* ea    = (const float*)d_in[2];
    const float* W1    = (const float*)d_in[3];
    const float* b1    = (const float*)d_in[4];
    const float* W2    = (const float*)d_in[5];
    const float* b2    = (const float*)d_in[6];
    const float* W3    = (const float*)d_in[7];
    const float* b3    = (const float*)d_in[8];
    const float* W4    = (const float*)d_in[9];
    const float* b4    = (const float*)d_in[10];
    const float* gamma = (const float*)d_in[11];
    const float* beta  = (const float*)d_in[12];
    const float* mean  = (const float*)d_in[13];
    const float* var   = (const float*)d_in[14];
    float* out = (float*)d_out;

    const int N = in_sizes[0] / D;   // 20000
    const int E = in_sizes[2] / D;   // 320000
    const int* src = ei;
    const int* dst = ei + E;

    // workspace layout (~129 MB):
    //   aggr  f32[N*H2]                 41.0 MB
    //   t     bf16[E*D]                 81.9 MB   (h bf16[N*H3]=41MB aliases t:
    //                                              node_mlp1 writes h AFTER
    //                                              edge_gemm consumed t)
    //   cursor/se/de/pe                  3.9 MB
    //   W1p..W4p packed bf16             ~2 MB
    char* ws = (char*)d_ws;
    float*  aggr = (float*)ws;
    ushort* t    = (ushort*)(ws + (size_t)N * H2 * 4);
    ushort* h    = t;   // alias, see above
    char*   p2   = (char*)(t + (size_t)E * D);
    int* cursor = (int*)p2;
    int* se     = cursor + N;
    int* de     = se + E;
    int* pe     = de + E;
    ushort* W1p = (ushort*)(pe + E);
    ushort* W2p = W1p + (size_t)(D  / 32) * (H1 / 16) * 512;
    ushort* W3p = W2p + (size_t)(H1 / 32) * (H2 / 16) * 512;
    ushort* W4p = W3p + (size_t)(K3 / 32) * (H3 / 16) * 512;

    hipMemsetAsync(aggr, 0, (size_t)N * H2 * sizeof(float), stream);
    hipMemsetAsync(cursor, 0, (size_t)N * sizeof(int), stream);

    pack_weights<<<(4096  + 255) / 256, 256, 0, stream>>>(W1, W1p, D,  H1);
    pack_weights<<<(16384 + 255) / 256, 256, 0, stream>>>(W2, W2p, H1, H2);
    pack_weights<<<(81920 + 255) / 256, 256, 0, stream>>>(W3, W3p, K3, H3);
    pack_weights<<<(16384 + 255) / 256, 256, 0, stream>>>(W4, W4p, H3, D);

    hist_kernel<<<(E + 255) / 256, 256, 0, stream>>>(dst, cursor, E);
    scan_kernel<<<1, 1024, 0, stream>>>(cursor, N);
    scatter_kernel<<<(E + 255) / 256, 256, 0, stream>>>(src, dst, cursor,
                                                        se, de, pe, E);

    gather_t<<<E / 16, 256, 0, stream>>>(x0, ea, se, pe, t);
    edge_gemm_mfma<<<E / TE, 256, 0, stream>>>(t, de, W1p, b1, W2p, b2, aggr);

    dim3 g1(N / TN, 2);
    node_mlp1_mfma<<<g1, 256, 0, stream>>>(x0, aggr, W3p, b3, h);
    node_mlp2_mfma<<<N / TN, 256, 0, stream>>>(h, x0, W4p, b4, gamma, beta, mean, var, out);
}

// Round 6
// 666.142 us; speedup vs baseline: 1.8079x; 1.0812x over previous
//
#include <hip/hip_runtime.h>

// MDDNet GNN layer — round 6: 8-wave blocks + halved per-wave acc to lift
// occupancy (VMEM-latency theory). Structure otherwise identical to R5.
// N=20000, E=320000, D=128, H1=256, H2=512, H3=1024, K3=640.

constexpr int D  = 128;
constexpr int H1 = 256;
constexpr int H2 = 512;
constexpr int H3 = 1024;
constexpr int K3 = D + H2;   // 640

typedef short  bf16x8 __attribute__((ext_vector_type(8)));
typedef ushort u16x8  __attribute__((ext_vector_type(8)));
typedef float  f32x4  __attribute__((ext_vector_type(4)));

__device__ __forceinline__ float leaky(float x) { return x >= 0.f ? x : 0.01f * x; }

__device__ __forceinline__ ushort f2bf(float f) {
    unsigned u = __float_as_uint(f);
    u += 0x7FFFu + ((u >> 16) & 1u);
    return (ushort)(u >> 16);
}

// LDS XOR swizzle (T2/G4)
__device__ __forceinline__ int swz(int row, int bytecol) {
    return bytecol ^ ((row & 7) << 4);
}

__device__ __forceinline__ f32x4 mfma16(bf16x8 a, bf16x8 b, f32x4 c) {
    return __builtin_amdgcn_mfma_f32_16x16x32_bf16(a, b, c, 0, 0, 0);
}

__device__ __forceinline__ void gload_lds16(const void* g, void* l) {
    __builtin_amdgcn_global_load_lds(
        (const __attribute__((address_space(1))) void*)g,
        (__attribute__((address_space(3))) void*)l, 16, 0, 0);
}

// ---------------------------------------------------------------------------
// Counting sort by dst (hist -> block scan -> scatter with pre-gather).
// ---------------------------------------------------------------------------
__global__ __launch_bounds__(256) void hist_kernel(
    const int* __restrict__ dst, int* __restrict__ cursor, int E)
{
    const int i = blockIdx.x * 256 + threadIdx.x;
    if (i < E) atomicAdd(&cursor[dst[i]], 1);
}

__global__ __launch_bounds__(1024) void scan_kernel(int* __restrict__ cursor, int n)
{
    __shared__ int sums[1024];
    const int tid  = threadIdx.x;
    const int base = tid * 20;
    int v[20];
    int s = 0;
    #pragma unroll
    for (int i = 0; i < 20; ++i) {
        const int idx = base + i;
        v[i] = (idx < n) ? cursor[idx] : 0;
        s += v[i];
    }
    sums[tid] = s;
    __syncthreads();
    int acc = s;
    for (int d = 1; d < 1024; d <<= 1) {
        const int t = (tid >= d) ? sums[tid - d] : 0;
        __syncthreads();
        acc += t;
        sums[tid] = acc;
        __syncthreads();
    }
    int run = acc - s;
    #pragma unroll
    for (int i = 0; i < 20; ++i) {
        const int idx = base + i;
        if (idx < n) cursor[idx] = run;
        run += v[i];
    }
}

__global__ __launch_bounds__(256) void scatter_kernel(
    const int* __restrict__ src, const int* __restrict__ dst,
    int* __restrict__ cursor, int* __restrict__ se, int* __restrict__ de,
    int* __restrict__ pe, int E)
{
    const int i = blockIdx.x * 256 + threadIdx.x;
    if (i < E) {
        const int d   = dst[i];
        const int pos = atomicAdd(&cursor[d], 1);
        se[pos] = src[i];
        de[pos] = d;
        pe[pos] = i;
    }
}

// ---------------------------------------------------------------------------
// gather_t: t[pos] = bf16(x0[se[pos]] * ea[pe[pos]]), pre-swizzled chunks.
// ---------------------------------------------------------------------------
__global__ __launch_bounds__(256) void gather_t(
    const float* __restrict__ x0, const float* __restrict__ ea,
    const int* __restrict__ se, const int* __restrict__ pe,
    ushort* __restrict__ t)
{
    const int gid  = blockIdx.x * 256 + threadIdx.x;
    const int e    = gid >> 4;
    const int slot = gid & 15;
    const int s = se[e];
    const int p = pe[e];
    const float4* xp = (const float4*)(x0 + (size_t)s * D + slot * 8);
    const float4* gp = (const float4*)(ea + (size_t)p * D + slot * 8);
    const float4 xa = xp[0], xb = xp[1];
    const float4 ga = gp[0], gb = gp[1];
    u16x8 u;
    u[0] = f2bf(xa.x * ga.x); u[1] = f2bf(xa.y * ga.y);
    u[2] = f2bf(xa.z * ga.z); u[3] = f2bf(xa.w * ga.w);
    u[4] = f2bf(xb.x * gb.x); u[5] = f2bf(xb.y * gb.y);
    u[6] = f2bf(xb.z * gb.z); u[7] = f2bf(xb.w * gb.w);
    const int slot_w = slot ^ (e & 7);
    *(u16x8*)(t + (size_t)e * D + slot_w * 8) = u;
}

// ---------------------------------------------------------------------------
// Pack fp32 W[K][Nc] into bf16 B-fragment tile order.
// ---------------------------------------------------------------------------
__global__ __launch_bounds__(256) void pack_weights(
    const float* __restrict__ W, ushort* __restrict__ Wp, int K, int Nc)
{
    const int KT    = K >> 5;
    const int total = (Nc >> 4) * KT * 64;
    const int idx   = blockIdx.x * 256 + threadIdx.x;
    if (idx >= total) return;
    const int l   = idx & 63;
    const int tt  = idx >> 6;
    const int ks  = tt % KT;
    const int ni  = tt / KT;
    const int col = ni * 16 + (l & 15);
    const int k0  = ks * 32 + (l >> 4) * 8;
    u16x8 u;
    #pragma unroll
    for (int j = 0; j < 8; ++j) u[j] = f2bf(W[(size_t)(k0 + j) * Nc + col]);
    *(u16x8*)(Wp + (size_t)idx * 8) = u;
}

// ---------------------------------------------------------------------------
// Dense edge GEMM, 8 waves / 512 threads. Per wave: GEMM1 2 ntiles (1 pass),
// GEMM2 2 passes x 2 ntiles (acc[4][2] = 32 VGPR). Run-combined atomics.
// ---------------------------------------------------------------------------
constexpr int TE = 64;

__global__ __launch_bounds__(512) void edge_gemm_mfma(
    const ushort* __restrict__ t, const int* __restrict__ de,
    const ushort* __restrict__ W1p, const float* __restrict__ b1,
    const ushort* __restrict__ W2p, const float* __restrict__ b2,
    float* __restrict__ aggr)
{
    __shared__ __align__(16) ushort t_lds[TE * D];     // 16 KB
    __shared__ __align__(16) ushort m1_lds[TE * H1];   // 32 KB
    __shared__ int didx[TE];

    const int tid  = threadIdx.x;
    const int e0   = blockIdx.x * TE;
    const int lane = tid & 63;
    const int w    = tid >> 6;     // 0..7
    const int lr   = lane & 15;
    const int lg   = lane >> 4;

    // async stage: 1024 x 16B chunks, 2 per thread
    const ushort* gsrc = t + (size_t)e0 * D;
    #pragma unroll
    for (int i = 0; i < 2; ++i) {
        const int c = (w * 2 + i) * 64 + lane;
        gload_lds16(gsrc + (size_t)c * 8, t_lds + (w * 2 + i) * 512);
    }
    if (tid < TE) didx[tid] = de[e0 + tid];
    __syncthreads();

    // GEMM1: m1[64][256] = leaky(t @ W1 + b1); wave owns ntiles {2w, 2w+1}
    {
        f32x4 acc[4][2];
        #pragma unroll
        for (int ntl = 0; ntl < 2; ++ntl) {
            const float b = b1[(w * 2 + ntl) * 16 + lr];
            #pragma unroll
            for (int mt = 0; mt < 4; ++mt) acc[mt][ntl] = (f32x4){b, b, b, b};
        }
        #pragma unroll
        for (int ks = 0; ks < 4; ++ks) {
            bf16x8 af[4];
            #pragma unroll
            for (int mt = 0; mt < 4; ++mt) {
                const int row = mt * 16 + lr;
                af[mt] = *(const bf16x8*)((const char*)t_lds + row * 256 +
                                          swz(row, ks * 64 + lg * 16));
            }
            #pragma unroll
            for (int ntl = 0; ntl < 2; ++ntl) {
                const bf16x8 bf = *(const bf16x8*)(W1p +
                    ((size_t)((w * 2 + ntl) * 4 + ks) * 64 + lane) * 8);
                #pragma unroll
                for (int mt = 0; mt < 4; ++mt)
                    acc[mt][ntl] = mfma16(af[mt], bf, acc[mt][ntl]);
            }
        }
        #pragma unroll
        for (int mt = 0; mt < 4; ++mt)
            #pragma unroll
            for (int ntl = 0; ntl < 2; ++ntl)
                #pragma unroll
                for (int r = 0; r < 4; ++r) {
                    const int row = mt * 16 + lg * 4 + r;
                    const int col = (w * 2 + ntl) * 16 + lr;
                    *(ushort*)((char*)m1_lds + row * 512 + swz(row, col * 2)) =
                        f2bf(leaky(acc[mt][ntl][r]));
                }
    }
    __syncthreads();

    // GEMM2: m2[64][512] = leaky(m1 @ W2 + b2) -> run-combined atomics.
    int dnode[4][4];
    #pragma unroll
    for (int mt = 0; mt < 4; ++mt)
        #pragma unroll
        for (int r = 0; r < 4; ++r)
            dnode[mt][r] = didx[mt * 16 + lg * 4 + r];

    #pragma unroll
    for (int p = 0; p < 2; ++p) {
        f32x4 acc[4][2];
        #pragma unroll
        for (int ntl = 0; ntl < 2; ++ntl) {
            const int nt = p * 16 + w * 2 + ntl;
            const float b = b2[nt * 16 + lr];
            #pragma unroll
            for (int mt = 0; mt < 4; ++mt) acc[mt][ntl] = (f32x4){b, b, b, b};
        }
        #pragma unroll
        for (int ks = 0; ks < 8; ++ks) {
            bf16x8 af[4];
            #pragma unroll
            for (int mt = 0; mt < 4; ++mt) {
                const int row = mt * 16 + lr;
                af[mt] = *(const bf16x8*)((const char*)m1_lds + row * 512 +
                                          swz(row, ks * 64 + lg * 16));
            }
            #pragma unroll
            for (int ntl = 0; ntl < 2; ++ntl) {
                const int nt = p * 16 + w * 2 + ntl;
                const bf16x8 bf = *(const bf16x8*)(W2p +
                    ((size_t)(nt * 8 + ks) * 64 + lane) * 8);
                #pragma unroll
                for (int mt = 0; mt < 4; ++mt)
                    acc[mt][ntl] = mfma16(af[mt], bf, acc[mt][ntl]);
            }
        }
        #pragma unroll
        for (int mt = 0; mt < 4; ++mt)
            #pragma unroll
            for (int ntl = 0; ntl < 2; ++ntl) {
                const int nt  = p * 16 + w * 2 + ntl;
                const int col = nt * 16 + lr;
                float s = leaky(acc[mt][ntl][0]);
                #pragma unroll
                for (int r = 1; r < 4; ++r) {
                    const float v = leaky(acc[mt][ntl][r]);
                    if (dnode[mt][r] == dnode[mt][r - 1]) {
                        s += v;
                    } else {
                        atomicAdd(&aggr[(size_t)dnode[mt][r - 1] * H2 + col], s);
                        s = v;
                    }
                }
                atomicAdd(&aggr[(size_t)dnode[mt][3] * H2 + col], s);
            }
    }
}

// ---------------------------------------------------------------------------
// h[N][1024] = bf16(leaky(concat(x0, aggr) @ W3 + b3)); 8 waves / 512 thr.
// ---------------------------------------------------------------------------
constexpr int TN = 32;

__global__ __launch_bounds__(512) void node_mlp1_mfma(
    const float* __restrict__ x0, const float* __restrict__ aggr,
    const ushort* __restrict__ W3p, const float* __restrict__ b3,
    ushort* __restrict__ h)
{
    __shared__ __align__(16) ushort a_lds[TN * K3];  // 40 KB
    const int tid  = threadIdx.x;
    const int n0   = blockIdx.x * TN;
    const int ch   = blockIdx.y;
    const int lane = tid & 63;
    const int w    = tid >> 6;     // 0..7
    const int lr   = lane & 15;
    const int lg   = lane >> 4;

    // stage 2560 x 16B chunks, 5 per thread
    #pragma unroll
    for (int i = 0; i < 5; ++i) {
        const int c    = i * 512 + tid;
        const int row  = c / 80;
        const int slot = c % 80;
        const float* sp = (slot < 16)
            ? x0   + (size_t)(n0 + row) * D  + slot * 8
            : aggr + (size_t)(n0 + row) * H2 + (slot - 16) * 8;
        const float4 va = ((const float4*)sp)[0];
        const float4 vb = ((const float4*)sp)[1];
        u16x8 u;
        u[0] = f2bf(va.x); u[1] = f2bf(va.y); u[2] = f2bf(va.z); u[3] = f2bf(va.w);
        u[4] = f2bf(vb.x); u[5] = f2bf(vb.y); u[6] = f2bf(vb.z); u[7] = f2bf(vb.w);
        *(u16x8*)((char*)a_lds + row * 1280 + swz(row, slot * 16)) = u;
    }
    __syncthreads();

    // wave w owns ntiles {4w..4w+3} of this 512-col half
    f32x4 acc[2][4];
    #pragma unroll
    for (int ntl = 0; ntl < 4; ++ntl) {
        const int colg = ch * 512 + (w * 4 + ntl) * 16 + lr;
        const float b = b3[colg];
        #pragma unroll
        for (int mt = 0; mt < 2; ++mt) acc[mt][ntl] = (f32x4){b, b, b, b};
    }
    for (int ks = 0; ks < 20; ++ks) {
        bf16x8 af[2];
        #pragma unroll
        for (int mt = 0; mt < 2; ++mt) {
            const int row = mt * 16 + lr;
            af[mt] = *(const bf16x8*)((const char*)a_lds + row * 1280 +
                                      swz(row, ks * 64 + lg * 16));
        }
        #pragma unroll
        for (int ntl = 0; ntl < 4; ++ntl) {
            const int nt = ch * 32 + w * 4 + ntl;
            const bf16x8 bf = *(const bf16x8*)(W3p +
                ((size_t)(nt * 20 + ks) * 64 + lane) * 8);
            #pragma unroll
            for (int mt = 0; mt < 2; ++mt)
                acc[mt][ntl] = mfma16(af[mt], bf, acc[mt][ntl]);
        }
    }
    #pragma unroll
    for (int mt = 0; mt < 2; ++mt)
        #pragma unroll
        for (int ntl = 0; ntl < 4; ++ntl) {
            const int colg = ch * 512 + (w * 4 + ntl) * 16 + lr;
            #pragma unroll
            for (int r = 0; r < 4; ++r) {
                const int row = n0 + mt * 16 + lg * 4 + r;
                h[(size_t)row * H3 + colg] = f2bf(leaky(acc[mt][ntl][r]));
            }
        }
}

// ---------------------------------------------------------------------------
// out = ((h @ W4 + b4)·BN + x0) / 2
// ---------------------------------------------------------------------------
__global__ __launch_bounds__(256) void node_mlp2_mfma(
    const ushort* __restrict__ h, const float* __restrict__ x0,
    const ushort* __restrict__ W4p, const float* __restrict__ b4,
    const float* __restrict__ gamma, const float* __restrict__ beta,
    const float* __restrict__ mean, const float* __restrict__ var,
    float* __restrict__ out)
{
    const int tid  = threadIdx.x;
    const int n0   = blockIdx.x * TN;
    const int lane = tid & 63;
    const int w    = tid >> 6;
    const int lr   = lane & 15;
    const int lg   = lane >> 4;

    f32x4 acc[2][2];
    #pragma unroll
    for (int ntl = 0; ntl < 2; ++ntl) {
        const float b = b4[(w * 2 + ntl) * 16 + lr];
        #pragma unroll
        for (int mt = 0; mt < 2; ++mt) acc[mt][ntl] = (f32x4){b, b, b, b};
    }
    for (int ks = 0; ks < 32; ++ks) {
        bf16x8 af[2];
        #pragma unroll
        for (int mt = 0; mt < 2; ++mt)
            af[mt] = *(const bf16x8*)(h + (size_t)(n0 + mt * 16 + lr) * H3 +
                                      ks * 32 + lg * 8);
        #pragma unroll
        for (int ntl = 0; ntl < 2; ++ntl) {
            const bf16x8 bf = *(const bf16x8*)(W4p +
                ((size_t)((w * 2 + ntl) * 32 + ks) * 64 + lane) * 8);
            #pragma unroll
            for (int mt = 0; mt < 2; ++mt)
                acc[mt][ntl] = mfma16(af[mt], bf, acc[mt][ntl]);
        }
    }
    #pragma unroll
    for (int ntl = 0; ntl < 2; ++ntl) {
        const int col = (w * 2 + ntl) * 16 + lr;
        const float sc = gamma[col] * rsqrtf(var[col] + 1e-5f);
        const float bo = beta[col] - mean[col] * sc;
        #pragma unroll
        for (int mt = 0; mt < 2; ++mt)
            #pragma unroll
            for (int r = 0; r < 4; ++r) {
                const int row = n0 + mt * 16 + lg * 4 + r;
                const float v = acc[mt][ntl][r] * sc + bo;
                out[(size_t)row * D + col] =
                    0.5f * (v + x0[(size_t)row * D + col]);
            }
    }
}

extern "C" void kernel_launch(void* const* d_in, const int* in_sizes, int n_in,
                              void* d_out, int out_size, void* d_ws, size_t ws_size,
                              hipStream_t stream)
{
    const float* x0    = (const float*)d_in[0];
    const int*   ei    = (const int*)d_in[1];
    const float* ea    = (const float*)d_in[2];
    const float* W1    = (const float*)d_in[3];
    const float* b1    = (const float*)d_in[4];
    const float* W2    = (const float*)d_in[5];
    const float* b2    = (const float*)d_in[6];
    const float* W3    = (const float*)d_in[7];
    const float* b3    = (const float*)d_in[8];
    const float* W4    = (const float*)d_in[9];
    const float* b4    = (const float*)d_in[10];
    const float* gamma = (const float*)d_in[11];
    const float* beta  = (const float*)d_in[12];
    const float* mean  = (const float*)d_in[13];
    const float* var   = (const float*)d_in[14];
    float* out = (float*)d_out;

    const int N = in_sizes[0] / D;   // 20000
    const int E = in_sizes[2] / D;   // 320000
    const int* src = ei;
    const int* dst = ei + E;

    char* ws = (char*)d_ws;
    float*  aggr = (float*)ws;
    ushort* t    = (ushort*)(ws + (size_t)N * H2 * 4);
    ushort* h    = t;   // alias: node_mlp1 writes h AFTER edge_gemm consumed t
    char*   p2   = (char*)(t + (size_t)E * D);
    int* cursor = (int*)p2;
    int* se     = cursor + N;
    int* de     = se + E;
    int* pe     = de + E;
    ushort* W1p = (ushort*)(pe + E);
    ushort* W2p = W1p + (size_t)(D  / 32) * (H1 / 16) * 512;
    ushort* W3p = W2p + (size_t)(H1 / 32) * (H2 / 16) * 512;
    ushort* W4p = W3p + (size_t)(K3 / 32) * (H3 / 16) * 512;

    hipMemsetAsync(aggr, 0, (size_t)N * H2 * sizeof(float), stream);
    hipMemsetAsync(cursor, 0, (size_t)N * sizeof(int), stream);

    pack_weights<<<(4096  + 255) / 256, 256, 0, stream>>>(W1, W1p, D,  H1);
    pack_weights<<<(16384 + 255) / 256, 256, 0, stream>>>(W2, W2p, H1, H2);
    pack_weights<<<(81920 + 255) / 256, 256, 0, stream>>>(W3, W3p, K3, H3);
    pack_weights<<<(16384 + 255) / 256, 256, 0, stream>>>(W4, W4p, H3, D);

    hist_kernel<<<(E + 255) / 256, 256, 0, stream>>>(dst, cursor, E);
    scan_kernel<<<1, 1024, 0, stream>>>(cursor, N);
    scatter_kernel<<<(E + 255) / 256, 256, 0, stream>>>(src, dst, cursor,
                                                        se, de, pe, E);

    gather_t<<<E / 16, 256, 0, stream>>>(x0, ea, se, pe, t);
    edge_gemm_mfma<<<E / TE, 512, 0, stream>>>(t, de, W1p, b1, W2p, b2, aggr);

    dim3 g1(N / TN, 2);
    node_mlp1_mfma<<<g1, 512, 0, stream>>>(x0, aggr, W3p, b3, h);
    node_mlp2_mfma<<<N / TN, 256, 0, stream>>>(h, x0, W4p, b4, gamma, beta, mean, var, out);
}